// Round 1
// baseline (566.030 us; speedup 1.0000x reference)
//
#include <hip/hip_runtime.h>

#define LRELU 0.1f
#define MSTR 516  // LDS row stride in halfs (512 + 4 pad -> conflict-free b64 reads)

typedef _Float16 h4 __attribute__((ext_vector_type(4)));
typedef _Float16 h8 __attribute__((ext_vector_type(8)));
typedef float f4 __attribute__((ext_vector_type(4)));

// ---------------- Stage A: grid feature softmax regression ----------------
// 32 WGs: one per (b, q) pair. Two-pass softmax over N=6912 in LDS.
__global__ __launch_bounds__(256) void k_gridfeat(
    const float* __restrict__ sound_loc, const float* __restrict__ grid_coors,
    const float* __restrict__ grid_0, const float* __restrict__ xyz_offset,
    const float* __restrict__ bandwidths, float* __restrict__ gf)
{
  const int N = 6912;
  __shared__ float s_lds[6912];
  __shared__ float red[256];
  int wg = blockIdx.x; int b = wg >> 1, q = wg & 1;
  int tid = threadIdx.x;
  float qx = sound_loc[b*6 + q*3 + 0];
  float qy = sound_loc[b*6 + q*3 + 1];
  float qz = sound_loc[b*6 + q*3 + 2];
  float lmax = -3.4e38f;
  for (int n = tid; n < N; n += 256) {
    float gx = grid_coors[n*3+0] + tanhf(xyz_offset[n*3+0]) * 0.1f;
    float gy = grid_coors[n*3+1] + tanhf(xyz_offset[n*3+1]) * 0.1f;
    float gz = grid_coors[n*3+2] + tanhf(xyz_offset[n*3+2]) * 0.1f;
    float bw = fminf(fmaxf(bandwidths[n], 0.1f), 0.5f);
    float dx = qx-gx, dy = qy-gy, dz = qz-gz;
    float d2 = dx*dx + dy*dy + dz*dz;
    float s = -d2 / (2.0f*bw*bw);
    s_lds[n] = s;
    lmax = fmaxf(lmax, s);
  }
  red[tid] = lmax; __syncthreads();
  for (int st = 128; st > 0; st >>= 1) {
    if (tid < st) red[tid] = fmaxf(red[tid], red[tid+st]);
    __syncthreads();
  }
  float mx = red[0]; __syncthreads();
  float lsum = 0.f;
  for (int n = tid; n < N; n += 256) {
    float e = expf(s_lds[n] - mx);
    s_lds[n] = e;
    lsum += e;
  }
  red[tid] = lsum; __syncthreads();
  for (int st = 128; st > 0; st >>= 1) {
    if (tid < st) red[tid] = red[tid] + red[tid+st];
    __syncthreads();
  }
  float total = red[0]; __syncthreads();
  // weighted sum: thread (g = tid>>6, c = tid&63) handles quarter g, channel c
  int c = tid & 63, g = tid >> 6;
  float acc = 0.f;
  for (int n = g*1728; n < (g+1)*1728; ++n)
    acc += s_lds[n] * grid_0[n*64 + c];
  red[tid] = acc; __syncthreads();
  if (tid < 64) {
    float v = (red[tid] + red[tid+64] + red[tid+128] + red[tid+192]) / total;
    gf[b*128 + q*64 + tid] = v;
  }
}

// ---------------- Pack weights fp32 -> fp16 fragment-linear ----------------
// Fragment layout per (kb, nb) block: 64 lanes x 8 elems contiguous.
// k = kb*32 + (l>>4)*4 + (e&3) + 16*(e>>2);  n = nb*16 + (l&15)
// Identical map is used for A-fragment loads, so the k-permutation cancels.
__global__ __launch_bounds__(256) void k_pack(
    const float* __restrict__ r1W1, const float* __restrict__ projW,
    const float* __restrict__ r1W2, const float* __restrict__ layersW,
    _Float16* __restrict__ dst)
{
  int fb = blockIdx.x; int t = threadIdx.x;
  const float* src; int K; long base; int rel;
  if (fb < 256)        { src = r1W1;  K = 248; base = 0;       rel = fb; }
  else if (fb < 512)   { src = projW; K = 248; base = 131072;  rel = fb - 256; }
  else if (fb < 1024)  { src = r1W2;  K = 512; base = 262144;  rel = fb - 512; }
  else { int L = (fb-1024) >> 9; src = layersW + (long)L*262144;
         K = 512; base = 524288 + (long)L*262144; rel = (fb-1024) & 511; }
  int kb = rel >> 5, nb = rel & 31;
  int l = t >> 2; int ep = (t & 3) << 1;            // e = ep, ep+1 (same k-half)
  int k0 = kb*32 + ((l>>4)<<2) + (ep & 3) + ((ep>>2)<<4);
  int n  = nb*16 + (l & 15);
  float v0 = (k0     < K) ? src[(long)k0*512 + n]     : 0.f;
  float v1 = (k0 + 1 < K) ? src[(long)(k0+1)*512 + n] : 0.f;
  _Float16* d = dst + base + (long)rel*512 + l*8 + ep;
  d[0] = (_Float16)v0; d[1] = (_Float16)v1;
}

// ---------------- Fused MLP ----------------
// 512 WGs x 512 threads (8 waves). 128 rows/WG. Wave w owns cols [w*64, w*64+64).
__global__ __launch_bounds__(512, 2) void k_mlp(
    const float* __restrict__ input_stuff, const float* __restrict__ gf,
    const _Float16* __restrict__ wp,
    const float* __restrict__ proj_b, const float* __restrict__ r1_b1,
    const float* __restrict__ r1_b2, const float* __restrict__ layers_b,
    const float* __restrict__ out_W, const float* __restrict__ out_b,
    _Float16* __restrict__ res_spill, float* __restrict__ out)
{
  __shared__ _Float16 A[128 * MSTR];   // 132,096 B
  const int tid = threadIdx.x;
  const int w = tid >> 6, l = tid & 63;
  const long R0 = (long)blockIdx.x * 128;
  const int b = (int)(R0 >> 12);       // rows per batch = 4096, 128 | 4096

  f4 acc[8][4];

  auto zero_acc = [&]() {
    #pragma unroll
    for (int mb = 0; mb < 8; ++mb)
      #pragma unroll
      for (int j = 0; j < 4; ++j)
        acc[mb][j] = (f4){0.f, 0.f, 0.f, 0.f};
  };

  auto stage_input = [&]() {
    // cols 0..127: grid feats (same per row within this WG's batch)
    // cols 128..247: input_stuff; cols 248..255: zero pad
    const float* inp = input_stuff + R0 * 120;
    for (int i = tid; i < 15360; i += 512) {
      int m = i / 120, j = i - m * 120;
      A[m*MSTR + 128 + j] = (_Float16)inp[i];
    }
    const float* g = gf + b * 128;
    for (int i = tid; i < 16384; i += 512) {
      int m = i >> 7, cc = i & 127;
      A[m*MSTR + cc] = (_Float16)g[cc];
    }
    for (int i = tid; i < 1024; i += 512) {
      int m = i >> 3, j = i & 7;
      A[m*MSTR + 248 + j] = (_Float16)0.f;
    }
  };

  auto matmul = [&](const _Float16* wbase, int KB) {
    for (int kb = 0; kb < KB; ++kb) {
      const _Float16* ab = &A[(l & 15)*MSTR + kb*32 + ((l >> 4) << 2)];
      h8 a[8];
      #pragma unroll
      for (int mb = 0; mb < 8; ++mb) {
        h4 lo = *(const h4*)(ab + mb*16*MSTR);
        h4 hi = *(const h4*)(ab + mb*16*MSTR + 16);
        a[mb] = __builtin_shufflevector(lo, hi, 0, 1, 2, 3, 4, 5, 6, 7);
      }
      const h8* wptr = (const h8*)wbase + (size_t)(kb*32 + (w << 2)) * 64 + l;
      #pragma unroll
      for (int j = 0; j < 4; ++j) {
        h8 bf = wptr[j * 64];
        #pragma unroll
        for (int mb = 0; mb < 8; ++mb)
          acc[mb][j] = __builtin_amdgcn_mfma_f32_16x16x32_f16(a[mb], bf, acc[mb][j], 0, 0, 0);
      }
    }
  };

  auto epilogue = [&](const float* bias, bool add_res, bool do_leaky) {
    #pragma unroll
    for (int mb = 0; mb < 8; ++mb) {
      int row0 = mb*16 + ((l >> 4) << 2);
      #pragma unroll
      for (int j = 0; j < 4; ++j) {
        int n = (w << 6) + (j << 4) + (l & 15);
        float bv = bias[n];
        #pragma unroll
        for (int r = 0; r < 4; ++r) {
          float v = acc[mb][j][r] + bv;
          if (add_res) v += (float)res_spill[(R0 + row0 + r)*512 + n];
          if (do_leaky) v = (v >= 0.f) ? v : LRELU * v;
          A[(row0 + r)*MSTR + n] = (_Float16)v;
        }
      }
    }
  };

  auto epilogue_res = [&](const float* bias) {
    #pragma unroll
    for (int mb = 0; mb < 8; ++mb) {
      int row0 = mb*16 + ((l >> 4) << 2);
      #pragma unroll
      for (int j = 0; j < 4; ++j) {
        int n = (w << 6) + (j << 4) + (l & 15);
        float bv = bias[n];
        #pragma unroll
        for (int r = 0; r < 4; ++r) {
          float v = acc[mb][j][r] + bv;
          res_spill[(R0 + row0 + r)*512 + n] = (_Float16)v;   // no leaky on res
        }
      }
    }
  };

  // --- residual path first: res = leaky(my_input@r1W1+b1)@r1W2 + b2 ---
  stage_input();
  __syncthreads();
  zero_acc(); matmul(wp + 0, 8);                 // r1_W1 (K=256 padded)
  __syncthreads();
  epilogue(r1_b1, false, true);                  // leaky
  __syncthreads();
  zero_acc(); matmul(wp + 262144, 16);           // r1_W2
  __syncthreads();                               // all A reads done
  epilogue_res(r1_b2);                           // spill res to global (f16)
  stage_input();                                 // restore my_input into A
  __syncthreads();
  // --- main chain ---
  zero_acc(); matmul(wp + 131072, 8);            // proj (K=256 padded)
  __syncthreads();
  epilogue(proj_b, false, true);                 // write leaky(h0)
  __syncthreads();
  for (int k = 0; k < 6; ++k) {
    zero_acc(); matmul(wp + 524288 + (size_t)k*262144, 16);
    __syncthreads();
    // out = leaky_prev @ Wk + bk (+ res at k==2); next layer consumes leaky,
    // except k==5 whose raw output feeds out_W.
    epilogue(layers_b + k*512, k == 2, k < 5);
    __syncthreads();
  }
  // --- final dot: out5 @ out_W + out_b ---
  {
    int r = tid >> 2, q = tid & 3;
    float s = 0.f;
    const _Float16* arow = &A[r*MSTR + q*128];
    const float* owq = out_W + q*128;
    for (int c = 0; c < 128; c += 4) {
      h4 v = *(const h4*)(arow + c);
      s += (float)v[0]*owq[c] + (float)v[1]*owq[c+1]
         + (float)v[2]*owq[c+2] + (float)v[3]*owq[c+3];
    }
    s += __shfl_xor(s, 1);
    s += __shfl_xor(s, 2);
    if (q == 0) out[R0 + r] = s + out_b[0];
  }
}

extern "C" void kernel_launch(void* const* d_in, const int* in_sizes, int n_in,
                              void* d_out, int out_size, void* d_ws, size_t ws_size,
                              hipStream_t stream) {
  const float* input_stuff = (const float*)d_in[0];
  const float* sound_loc   = (const float*)d_in[1];
  const float* grid_coors  = (const float*)d_in[2];
  const float* grid_0      = (const float*)d_in[3];
  const float* xyz_offset  = (const float*)d_in[4];
  const float* bandwidths  = (const float*)d_in[5];
  const float* proj_W  = (const float*)d_in[6];
  const float* proj_b  = (const float*)d_in[7];
  const float* r1_W1   = (const float*)d_in[8];
  const float* r1_b1   = (const float*)d_in[9];
  const float* r1_W2   = (const float*)d_in[10];
  const float* r1_b2   = (const float*)d_in[11];
  const float* layers_W = (const float*)d_in[12];
  const float* layers_b = (const float*)d_in[13];
  const float* out_W   = (const float*)d_in[14];
  const float* out_b   = (const float*)d_in[15];

  char* ws = (char*)d_ws;
  float*     gf  = (float*)ws;                   // [16][128] fp32   (8 KB)
  _Float16*  wp  = (_Float16*)(ws + (1 << 20));  // packed weights   (4 MB)
  _Float16*  res = (_Float16*)(ws + (8 << 20));  // res spill f16    (64 MB)
  float* out = (float*)d_out;

  hipLaunchKernelGGL(k_gridfeat, dim3(32), dim3(256), 0, stream,
                     sound_loc, grid_coors, grid_0, xyz_offset, bandwidths, gf);
  hipLaunchKernelGGL(k_pack, dim3(4096), dim3(256), 0, stream,
                     r1_W1, proj_W, r1_W2, layers_W, wp);
  hipLaunchKernelGGL(k_mlp, dim3(512), dim3(512), 0, stream,
                     input_stuff, gf, wp, proj_b, r1_b1, r1_b2, layers_b,
                     out_W, out_b, res, out);
}

// Round 6
// 461.890 us; speedup vs baseline: 1.2255x; 1.2255x over previous
//
#include <hip/hip_runtime.h>

#define LRELU 0.1f
#define MSTR 520  // LDS row stride in halfs (1040 B = 65*16 -> 16B-aligned rows)

typedef _Float16 h4 __attribute__((ext_vector_type(4)));
typedef _Float16 h8 __attribute__((ext_vector_type(8)));
typedef float f4 __attribute__((ext_vector_type(4)));

struct KB8  { static constexpr int value = 8; };
struct KB16 { static constexpr int value = 16; };

// ---------------- Stage A: grid feature softmax regression ----------------
__global__ __launch_bounds__(256) void k_gridfeat(
    const float* __restrict__ sound_loc, const float* __restrict__ grid_coors,
    const float* __restrict__ grid_0, const float* __restrict__ xyz_offset,
    const float* __restrict__ bandwidths, float* __restrict__ gf)
{
  const int N = 6912;
  __shared__ float s_lds[6912];
  __shared__ float red[256];
  int wg = blockIdx.x; int b = wg >> 1, q = wg & 1;
  int tid = threadIdx.x;
  float qx = sound_loc[b*6 + q*3 + 0];
  float qy = sound_loc[b*6 + q*3 + 1];
  float qz = sound_loc[b*6 + q*3 + 2];
  float lmax = -3.4e38f;
  for (int n = tid; n < N; n += 256) {
    float gx = grid_coors[n*3+0] + tanhf(xyz_offset[n*3+0]) * 0.1f;
    float gy = grid_coors[n*3+1] + tanhf(xyz_offset[n*3+1]) * 0.1f;
    float gz = grid_coors[n*3+2] + tanhf(xyz_offset[n*3+2]) * 0.1f;
    float bw = fminf(fmaxf(bandwidths[n], 0.1f), 0.5f);
    float dx = qx-gx, dy = qy-gy, dz = qz-gz;
    float d2 = dx*dx + dy*dy + dz*dz;
    float s = -d2 / (2.0f*bw*bw);
    s_lds[n] = s;
    lmax = fmaxf(lmax, s);
  }
  red[tid] = lmax; __syncthreads();
  for (int st = 128; st > 0; st >>= 1) {
    if (tid < st) red[tid] = fmaxf(red[tid], red[tid+st]);
    __syncthreads();
  }
  float mx = red[0]; __syncthreads();
  float lsum = 0.f;
  for (int n = tid; n < N; n += 256) {
    float e = expf(s_lds[n] - mx);
    s_lds[n] = e;
    lsum += e;
  }
  red[tid] = lsum; __syncthreads();
  for (int st = 128; st > 0; st >>= 1) {
    if (tid < st) red[tid] = red[tid] + red[tid+st];
    __syncthreads();
  }
  float total = red[0]; __syncthreads();
  // weighted sum: thread (g = tid>>6, c = tid&63): quarter g, channel c
  int c = tid & 63, g = tid >> 6;
  float a0 = 0.f, a1 = 0.f, a2 = 0.f, a3 = 0.f;
  int n0 = g * 1728;
  for (int n = n0; n < n0 + 1728; n += 4) {
    a0 += s_lds[n+0] * grid_0[(n+0)*64 + c];
    a1 += s_lds[n+1] * grid_0[(n+1)*64 + c];
    a2 += s_lds[n+2] * grid_0[(n+2)*64 + c];
    a3 += s_lds[n+3] * grid_0[(n+3)*64 + c];
  }
  red[tid] = (a0 + a1) + (a2 + a3); __syncthreads();
  if (tid < 64) {
    float v = (red[tid] + red[tid+64] + red[tid+128] + red[tid+192]) / total;
    gf[b*128 + q*64 + tid] = v;
  }
}

// ---------------- Pack weights fp32 -> fp16 fragment-linear ----------------
// Fragment (kb, nb), 64 lanes x 8 contiguous halfs:
//   element (l, e) = W[kb*32 + (l>>4)*8 + e][nb*16 + (l&15)]
// Same k-map is used for the A-fragment ds_read_b128, so the permutation
// cancels in the contraction.
// One WG per kb-block: coalesced float4 loads -> LDS transpose -> coalesced
// h8 stores.
__global__ __launch_bounds__(256) void k_pack(
    const float* __restrict__ r1W1, const float* __restrict__ projW,
    const float* __restrict__ r1W2, const float* __restrict__ layersW,
    _Float16* __restrict__ dst)
{
  __shared__ _Float16 T[512][40];   // [n][kk], stride 40 halfs = 80 B
  int wg = blockIdx.x, t = threadIdx.x;
  const float* src; int K; long base; int kb;
  if (wg < 8)       { src = r1W1;  K = 248; base = 0;      kb = wg; }
  else if (wg < 16) { src = projW; K = 248; base = 131072; kb = wg - 8; }
  else if (wg < 32) { src = r1W2;  K = 512; base = 262144; kb = wg - 16; }
  else { int L = (wg - 32) >> 4; src = layersW + (long)L*262144;
         K = 512; base = 524288 + (long)L*262144; kb = (wg - 32) & 15; }
  for (int i4 = t; i4 < 4096; i4 += 256) {
    int kk = i4 >> 7, c4 = (i4 & 127) << 2;
    int k = kb*32 + kk;
    float4 v = (k < K) ? *(const float4*)&src[(long)k*512 + c4]
                       : make_float4(0.f, 0.f, 0.f, 0.f);
    T[c4+0][kk] = (_Float16)v.x; T[c4+1][kk] = (_Float16)v.y;
    T[c4+2][kk] = (_Float16)v.z; T[c4+3][kk] = (_Float16)v.w;
  }
  __syncthreads();
  _Float16* d = dst + base + (long)kb*32*512;
  for (int o = t; o < 2048; o += 256) {
    int nb = o >> 6, l = o & 63;
    h8 v = *(const h8*)&T[nb*16 + (l&15)][(l>>4) << 3];
    *(h8*)&d[(long)nb*512 + l*8] = v;
  }
}

// ---------------- Fused MLP ----------------
// 512 WGs x 512 threads (8 waves). 128 rows/WG. Wave w owns cols [w*64, w*64+64).
__global__ __launch_bounds__(512, 2) void k_mlp(
    const float* __restrict__ input_stuff, const float* __restrict__ gf,
    const _Float16* __restrict__ wp,
    const float* __restrict__ proj_b, const float* __restrict__ r1_b1,
    const float* __restrict__ r1_b2, const float* __restrict__ layers_b,
    const float* __restrict__ out_W, const float* __restrict__ out_b,
    _Float16* __restrict__ res_spill, float* __restrict__ out)
{
  __shared__ _Float16 A[128 * MSTR];   // 133,120 B -> 1 block/CU
  const int tid = threadIdx.x;
  const int w = tid >> 6, l = tid & 63;
  const long R0 = (long)blockIdx.x * 128;
  const int b = (int)(R0 >> 12);       // 128 | 4096, no WG crosses a batch

  f4 acc[8][4];

  auto zero_acc = [&]() {
    #pragma unroll
    for (int mb = 0; mb < 8; ++mb)
      #pragma unroll
      for (int j = 0; j < 4; ++j)
        acc[mb][j] = (f4){0.f, 0.f, 0.f, 0.f};
  };

  auto stage_input = [&]() {
    // cols 0..127 grid feats (broadcast per batch), 128..247 input, 248..255 zero
    const float* inp = input_stuff + R0 * 120;
    for (int i4 = tid; i4 < 3840; i4 += 512) {        // 128 rows x 30 float4
      int m = i4 / 30, c4 = i4 - m * 30;
      float4 v = *(const float4*)&inp[(m*120 + c4*4)];
      h4 hv = { (_Float16)v.x, (_Float16)v.y, (_Float16)v.z, (_Float16)v.w };
      *(h4*)&A[m*MSTR + 128 + c4*4] = hv;
    }
    const float* g = gf + b * 128;
    for (int i4 = tid; i4 < 4096; i4 += 512) {        // 128 rows x 32 float4
      int m = i4 >> 5, c4 = i4 & 31;
      float4 v = *(const float4*)&g[c4*4];
      h4 hv = { (_Float16)v.x, (_Float16)v.y, (_Float16)v.z, (_Float16)v.w };
      *(h4*)&A[m*MSTR + c4*4] = hv;
    }
    if (tid < 128) {
      h8 z = {};
      *(h8*)&A[tid*MSTR + 248] = z;
    }
  };

  // A-fragment: lane l, tile mb: ds_read_b128 of rows (l&15)+mb*16,
  // halfs kb*32 + (l>>4)*8 .. +8  (same k-map as packed B).
  auto matmul = [&](const _Float16* __restrict__ wbase, auto KBc) {
    constexpr int KB = KBc.value;
    const _Float16* abase = A + (l & 15)*MSTR + ((l >> 4) << 3);
    const h8* wb = (const h8*)wbase;
    h8 bb[2][4];
    #pragma unroll
    for (int j = 0; j < 4; ++j)
      bb[0][j] = wb[((w << 2) + j)*64 + l];
    #pragma unroll 2
    for (int kb = 0; kb < KB; ++kb) {
      if (kb + 1 < KB) {
        #pragma unroll
        for (int j = 0; j < 4; ++j)
          bb[(kb+1) & 1][j] = wb[((kb+1)*32 + (w << 2) + j)*64 + l];
      }
      h8 a[8];
      #pragma unroll
      for (int mb = 0; mb < 8; ++mb)
        a[mb] = *(const h8*)(abase + mb*16*MSTR + kb*32);
      #pragma unroll
      for (int j = 0; j < 4; ++j)
        #pragma unroll
        for (int mb = 0; mb < 8; ++mb)
          acc[mb][j] = __builtin_amdgcn_mfma_f32_16x16x32_f16(a[mb], bb[kb & 1][j], acc[mb][j], 0, 0, 0);
    }
  };

  // res spill: per-lane contiguous 128 halfs at ((wg*8+w)*64+l)*128,
  // element index = mb*16 + j*4 + r  -> 16 coalesced dwordx4 per lane.
  _Float16* myres = res_spill + ((long)(blockIdx.x*8 + w)*64 + l) * 128;

  auto epilogue = [&](const float* bias, bool add_res, bool do_leaky) {
    h8 r0[8], r1[8];
    if (add_res) {
      #pragma unroll
      for (int mb = 0; mb < 8; ++mb) {
        r0[mb] = *(const h8*)(myres + mb*16);
        r1[mb] = *(const h8*)(myres + mb*16 + 8);
      }
    }
    #pragma unroll
    for (int mb = 0; mb < 8; ++mb) {
      int row0 = mb*16 + ((l >> 4) << 2);
      #pragma unroll
      for (int j = 0; j < 4; ++j) {
        int n = (w << 6) + (j << 4) + (l & 15);
        float bv = bias[n];
        #pragma unroll
        for (int r = 0; r < 4; ++r) {
          float v = acc[mb][j][r] + bv;
          if (add_res) {
            int idx = j*4 + r;
            v += (idx < 8) ? (float)r0[mb][idx] : (float)r1[mb][idx - 8];
          }
          if (do_leaky) v = (v >= 0.f) ? v : LRELU * v;
          A[(row0 + r)*MSTR + n] = (_Float16)v;
        }
      }
    }
  };

  auto epilogue_res = [&](const float* bias) {
    #pragma unroll
    for (int mb = 0; mb < 8; ++mb) {
      float vals[16];
      #pragma unroll
      for (int j = 0; j < 4; ++j) {
        int n = (w << 6) + (j << 4) + (l & 15);
        float bv = bias[n];
        #pragma unroll
        for (int r = 0; r < 4; ++r)
          vals[j*4 + r] = acc[mb][j][r] + bv;
      }
      h8 x0, x1;
      #pragma unroll
      for (int e = 0; e < 8; ++e) { x0[e] = (_Float16)vals[e]; x1[e] = (_Float16)vals[e+8]; }
      *(h8*)(myres + mb*16) = x0;
      *(h8*)(myres + mb*16 + 8) = x1;
    }
  };

  // --- residual path: res = leaky(my_input@r1W1+b1)@r1W2 + b2 ---
  stage_input();
  __syncthreads();
  zero_acc(); matmul(wp + 0, KB8{});               // r1_W1 (K=256 padded)
  __syncthreads();
  epilogue(r1_b1, false, true);
  __syncthreads();
  zero_acc(); matmul(wp + 262144, KB16{});         // r1_W2
  __syncthreads();
  epilogue_res(r1_b2);                             // -> global (coalesced f16)
  stage_input();                                   // restore my_input
  __syncthreads();
  // --- main chain ---
  zero_acc(); matmul(wp + 131072, KB8{});          // proj
  __syncthreads();
  epilogue(proj_b, false, true);
  __syncthreads();
  for (int k = 0; k < 6; ++k) {
    zero_acc();
    matmul(wp + 524288 + (size_t)k*262144, KB16{});
    __syncthreads();
    epilogue(layers_b + k*512, k == 2, k < 5);     // res added at k==2
    __syncthreads();
  }
  // --- final dot: out5 @ out_W + out_b ---
  {
    int r = tid >> 2, q = tid & 3;
    float s = 0.f;
    const _Float16* arow = &A[r*MSTR + q*128];
    const float* owq = out_W + q*128;
    for (int c = 0; c < 128; c += 4) {
      h4 v = *(const h4*)(arow + c);
      s += (float)v[0]*owq[c] + (float)v[1]*owq[c+1]
         + (float)v[2]*owq[c+2] + (float)v[3]*owq[c+3];
    }
    s += __shfl_xor(s, 1);
    s += __shfl_xor(s, 2);
    if (q == 0) out[R0 + r] = s + out_b[0];
  }
}

extern "C" void kernel_launch(void* const* d_in, const int* in_sizes, int n_in,
                              void* d_out, int out_size, void* d_ws, size_t ws_size,
                              hipStream_t stream) {
  const float* input_stuff = (const float*)d_in[0];
  const float* sound_loc   = (const float*)d_in[1];
  const float* grid_coors  = (const float*)d_in[2];
  const float* grid_0      = (const float*)d_in[3];
  const float* xyz_offset  = (const float*)d_in[4];
  const float* bandwidths  = (const float*)d_in[5];
  const float* proj_W  = (const float*)d_in[6];
  const float* proj_b  = (const float*)d_in[7];
  const float* r1_W1   = (const float*)d_in[8];
  const float* r1_b1   = (const float*)d_in[9];
  const float* r1_W2   = (const float*)d_in[10];
  const float* r1_b2   = (const float*)d_in[11];
  const float* layers_W = (const float*)d_in[12];
  const float* layers_b = (const float*)d_in[13];
  const float* out_W   = (const float*)d_in[14];
  const float* out_b   = (const float*)d_in[15];

  char* ws = (char*)d_ws;
  float*     gf  = (float*)ws;                   // [16][128] fp32   (8 KB)
  _Float16*  wp  = (_Float16*)(ws + (1 << 20));  // packed weights   (4 MB)
  _Float16*  res = (_Float16*)(ws + (8 << 20));  // res spill f16    (64 MB)
  float* out = (float*)d_out;

  hipLaunchKernelGGL(k_gridfeat, dim3(32), dim3(256), 0, stream,
                     sound_loc, grid_coors, grid_0, xyz_offset, bandwidths, gf);
  hipLaunchKernelGGL(k_pack, dim3(128), dim3(256), 0, stream,
                     r1_W1, proj_W, r1_W2, layers_W, wp);
  hipLaunchKernelGGL(k_mlp, dim3(512), dim3(512), 0, stream,
                     input_stuff, gf, wp, proj_b, r1_b1, r1_b2, layers_b,
                     out_W, out_b, res, out);
}

// Round 9
// 418.751 us; speedup vs baseline: 1.3517x; 1.1030x over previous
//
#include <hip/hip_runtime.h>

#define LRELU 0.1f
#define MSTR 520  // LDS row stride in halfs (1040 B)

typedef _Float16 h4 __attribute__((ext_vector_type(4)));
typedef _Float16 h8 __attribute__((ext_vector_type(8)));
typedef __fp16 fp16x2 __attribute__((ext_vector_type(2)));
typedef float f4 __attribute__((ext_vector_type(4)));

struct KB8  { static constexpr int value = 8; };
struct KB16 { static constexpr int value = 16; };

// ---------------- Stage A1: softmax weights over N=6912 grid points ----------
// 32 WGs: one per (b,q). Writes normalized weights wn[bq][6912].
__global__ __launch_bounds__(256) void k_gridA(
    const float* __restrict__ sound_loc, const float* __restrict__ grid_coors,
    const float* __restrict__ xyz_offset, const float* __restrict__ bandwidths,
    float* __restrict__ wn)
{
  const int N = 6912;
  __shared__ float s_lds[6912];
  __shared__ float red[256];
  int bq = blockIdx.x; int b = bq >> 1, q = bq & 1;
  int tid = threadIdx.x;
  float qx = sound_loc[b*6 + q*3 + 0];
  float qy = sound_loc[b*6 + q*3 + 1];
  float qz = sound_loc[b*6 + q*3 + 2];
  float lmax = -3.4e38f;
  for (int n = tid; n < N; n += 256) {
    float gx = grid_coors[n*3+0] + tanhf(xyz_offset[n*3+0]) * 0.1f;
    float gy = grid_coors[n*3+1] + tanhf(xyz_offset[n*3+1]) * 0.1f;
    float gz = grid_coors[n*3+2] + tanhf(xyz_offset[n*3+2]) * 0.1f;
    float bw = fminf(fmaxf(bandwidths[n], 0.1f), 0.5f);
    float dx = qx-gx, dy = qy-gy, dz = qz-gz;
    float s = -(dx*dx + dy*dy + dz*dz) / (2.0f*bw*bw);
    s_lds[n] = s;
    lmax = fmaxf(lmax, s);
  }
  red[tid] = lmax; __syncthreads();
  for (int st = 128; st > 0; st >>= 1) {
    if (tid < st) red[tid] = fmaxf(red[tid], red[tid+st]);
    __syncthreads();
  }
  float mx = red[0]; __syncthreads();
  float lsum = 0.f;
  for (int n = tid; n < N; n += 256) {
    float e = expf(s_lds[n] - mx);
    s_lds[n] = e;
    lsum += e;
  }
  red[tid] = lsum; __syncthreads();
  for (int st = 128; st > 0; st >>= 1) {
    if (tid < st) red[tid] = red[tid] + red[tid+st];
    __syncthreads();
  }
  float inv = 1.0f / red[0]; __syncthreads();
  for (int n = tid; n < N; n += 256)
    wn[bq*6912 + n] = s_lds[n] * inv;
}

// ---------------- Stage A2: gf[bq][c] = sum_n wn[bq][n]*grid_0[n][c] --------
// Grid (16 chunks, 32 bq): 512 WGs. atomicAdd into zero-init gf.
__global__ __launch_bounds__(256) void k_gridB(
    const float* __restrict__ wn, const float* __restrict__ grid_0,
    float* __restrict__ gf)
{
  int chunk = blockIdx.x, bq = blockIdx.y;
  int t = threadIdx.x, c = t & 63, g = t >> 6;
  int n0 = chunk*432 + g*108;
  const float* wrow = wn + bq*6912 + n0;
  const float* g0 = grid_0 + (long)n0*64 + c;
  float a0 = 0.f, a1 = 0.f;
  for (int i = 0; i < 108; i += 2) {
    a0 += wrow[i]   * g0[(long)i*64];
    a1 += wrow[i+1] * g0[(long)(i+1)*64];
  }
  __shared__ float red[256];
  red[t] = a0 + a1; __syncthreads();
  if (t < 64) {
    float v = red[t] + red[t+64] + red[t+128] + red[t+192];
    int b = bq >> 1, q = bq & 1;
    atomicAdd(&gf[b*128 + q*64 + c], v);
  }
}

// ---------------- Pack weights fp32 -> fp16 fragment-linear ----------------
// Fragment (kb, nb), 64 lanes x 8 contiguous halfs:
//   element (l, e) = W[kb*32 + (l>>4)*8 + e][nb*16 + (l&15)]
// Used as MFMA *A-operand* (weights): row(i)=l&15 -> n, k=(l>>4)*8+e.
// Activations read from LDS use the same k-map, so the permutation cancels.
__global__ __launch_bounds__(256) void k_pack(
    const float* __restrict__ r1W1, const float* __restrict__ projW,
    const float* __restrict__ r1W2, const float* __restrict__ layersW,
    _Float16* __restrict__ dst)
{
  __shared__ _Float16 T[512][40];   // [n][kk], stride 40 halfs = 80 B
  int wg = blockIdx.x, t = threadIdx.x;
  const float* src; int K; long base; int kb;
  if (wg < 8)       { src = r1W1;  K = 248; base = 0;      kb = wg; }
  else if (wg < 16) { src = projW; K = 248; base = 131072; kb = wg - 8; }
  else if (wg < 32) { src = r1W2;  K = 512; base = 262144; kb = wg - 16; }
  else { int L = (wg - 32) >> 4; src = layersW + (long)L*262144;
         K = 512; base = 524288 + (long)L*262144; kb = (wg - 32) & 15; }
  for (int i4 = t; i4 < 4096; i4 += 256) {
    int kk = i4 >> 7, c4 = (i4 & 127) << 2;
    int k = kb*32 + kk;
    float4 v = (k < K) ? *(const float4*)&src[(long)k*512 + c4]
                       : make_float4(0.f, 0.f, 0.f, 0.f);
    T[c4+0][kk] = (_Float16)v.x; T[c4+1][kk] = (_Float16)v.y;
    T[c4+2][kk] = (_Float16)v.z; T[c4+3][kk] = (_Float16)v.w;
  }
  __syncthreads();
  _Float16* d = dst + base + (long)kb*32*512;
  for (int o = t; o < 2048; o += 256) {
    int nb = o >> 6, l = o & 63;
    h8 v = *(const h8*)&T[nb*16 + (l&15)][(l>>4) << 3];
    *(h8*)&d[(long)nb*512 + l*8] = v;
  }
}

// ---------------- Fused MLP (transposed MFMA roles) ----------------
// 512 WGs x 512 threads (8 waves). 128 rows/WG. Wave w owns cols [w*64, w*64+64).
// D = Wfrag(A-op) x Actfrag(B-op): lane owns act-row m = l&15 (per m-tile) and
// 4 consecutive output channels per reg -> b64 epilogue writes.
__global__ __launch_bounds__(512, 2) void k_mlp(
    const float* __restrict__ input_stuff, const float* __restrict__ gf,
    const _Float16* __restrict__ wp,
    const float* __restrict__ proj_b, const float* __restrict__ r1_b1,
    const float* __restrict__ r1_b2, const float* __restrict__ layers_b,
    const float* __restrict__ out_W, const float* __restrict__ out_b,
    _Float16* __restrict__ res_spill, float* __restrict__ out)
{
  __shared__ _Float16 A[128 * MSTR];   // 133,120 B -> 1 block/CU
  const int tid = threadIdx.x;
  const int w = tid >> 6, l = tid & 63;
  const int q = l >> 4, r = l & 15;
  const long R0 = (long)blockIdx.x * 128;
  const int b = (int)(R0 >> 12);       // 128 | 4096

  f4 acc[8][4];

  auto zero_acc = [&]() {
    #pragma unroll
    for (int mb = 0; mb < 8; ++mb)
      #pragma unroll
      for (int j = 0; j < 4; ++j)
        acc[mb][j] = (f4){0.f, 0.f, 0.f, 0.f};
  };

  auto stage_input = [&]() {
    const float* inp = input_stuff + R0 * 120;
    for (int i4 = tid; i4 < 3840; i4 += 512) {        // 128 rows x 30 float4
      int m = i4 / 30, c4 = i4 - m * 30;
      float4 v = *(const float4*)&inp[(m*120 + c4*4)];
      h4 hv = { (_Float16)v.x, (_Float16)v.y, (_Float16)v.z, (_Float16)v.w };
      *(h4*)&A[m*MSTR + 128 + c4*4] = hv;
    }
    const float* g = gf + b * 128;
    for (int i4 = tid; i4 < 4096; i4 += 512) {        // 128 rows x 32 float4
      int m = i4 >> 5, c4 = i4 & 31;
      float4 v = *(const float4*)&g[c4*4];
      h4 hv = { (_Float16)v.x, (_Float16)v.y, (_Float16)v.z, (_Float16)v.w };
      *(h4*)&A[m*MSTR + c4*4] = hv;
    }
    if (tid < 128) {
      h8 z = {};
      *(h8*)&A[tid*MSTR + 248] = z;
    }
  };

  // B-operand (activation): lane l, m-tile mb: ds_read_b128 of row mb*16+r,
  // halfs kb*32 + q*8 .. +8. A-operand (weights): packed fragment, same k-map.
  auto matmul = [&](const _Float16* __restrict__ wbase, auto KBc) {
    constexpr int KB = KBc.value;
    const _Float16* abase = A + r*MSTR + (q << 3);
    const h8* wb = (const h8*)wbase;
    h8 bb[2][4];
    #pragma unroll
    for (int j = 0; j < 4; ++j)
      bb[0][j] = wb[((w << 2) + j)*64 + l];
    #pragma unroll 2
    for (int kb = 0; kb < KB; ++kb) {
      if (kb + 1 < KB) {
        #pragma unroll
        for (int j = 0; j < 4; ++j)
          bb[(kb+1) & 1][j] = wb[((kb+1)*32 + (w << 2) + j)*64 + l];
      }
      h8 a[8];
      #pragma unroll
      for (int mb = 0; mb < 8; ++mb)
        a[mb] = *(const h8*)(abase + mb*16*MSTR + kb*32);
      #pragma unroll
      for (int j = 0; j < 4; ++j)
        #pragma unroll
        for (int mb = 0; mb < 8; ++mb)
          acc[mb][j] = __builtin_amdgcn_mfma_f32_16x16x32_f16(
              bb[kb & 1][j], a[mb], acc[mb][j], 0, 0, 0);  // weights = A-op
    }
  };

  // res spill: per-lane contiguous 128 halfs; element (mb,j,s) at mb*16+j*4+s.
  _Float16* myres = res_spill + ((long)(blockIdx.x*8 + w)*64 + l) * 128;

  // lane's output: m = mb*16 + r, n = w*64 + j*16 + q*4 + s  (s = reg 0..3)
  auto epilogue = [&](const float* bias, bool add_res, bool do_leaky) {
    h8 r0[8], r1[8];
    if (add_res) {
      #pragma unroll
      for (int mb = 0; mb < 8; ++mb) {
        r0[mb] = *(const h8*)(myres + mb*16);
        r1[mb] = *(const h8*)(myres + mb*16 + 8);
      }
    }
    #pragma unroll
    for (int j = 0; j < 4; ++j) {
      float4 bv = *(const float4*)&bias[(w << 6) + (j << 4) + q*4];
      #pragma unroll
      for (int mb = 0; mb < 8; ++mb) {
        f4 v = acc[mb][j];
        v[0] += bv.x; v[1] += bv.y; v[2] += bv.z; v[3] += bv.w;
        if (add_res) {
          #pragma unroll
          for (int s = 0; s < 4; ++s) {
            int idx = j*4 + s;
            v[s] += (idx < 8) ? (float)r0[mb][idx] : (float)r1[mb][idx - 8];
          }
        }
        if (do_leaky) {
          #pragma unroll
          for (int s = 0; s < 4; ++s) v[s] = fmaxf(v[s], LRELU * v[s]);
        }
        fp16x2 p0 = __builtin_amdgcn_cvt_pkrtz(v[0], v[1]);
        fp16x2 p1 = __builtin_amdgcn_cvt_pkrtz(v[2], v[3]);
        h4 hv = { (_Float16)p0[0], (_Float16)p0[1],
                  (_Float16)p1[0], (_Float16)p1[1] };
        *(h4*)&A[(mb*16 + r)*MSTR + (w << 6) + (j << 4) + q*4] = hv;
      }
    }
  };

  auto epilogue_res = [&](const float* bias) {
    #pragma unroll
    for (int mb = 0; mb < 8; ++mb) {
      float vals[16];
      #pragma unroll
      for (int j = 0; j < 4; ++j) {
        float4 bv = *(const float4*)&bias[(w << 6) + (j << 4) + q*4];
        vals[j*4+0] = acc[mb][j][0] + bv.x;
        vals[j*4+1] = acc[mb][j][1] + bv.y;
        vals[j*4+2] = acc[mb][j][2] + bv.z;
        vals[j*4+3] = acc[mb][j][3] + bv.w;
      }
      h8 x0, x1;
      #pragma unroll
      for (int e = 0; e < 8; ++e) { x0[e] = (_Float16)vals[e]; x1[e] = (_Float16)vals[e+8]; }
      *(h8*)(myres + mb*16) = x0;
      *(h8*)(myres + mb*16 + 8) = x1;
    }
  };

  // --- residual path: res = leaky(my_input@r1W1+b1)@r1W2 + b2 ---
  stage_input();
  __syncthreads();
  zero_acc(); matmul(wp + 0, KB8{});               // r1_W1 (K=256 padded)
  __syncthreads();
  epilogue(r1_b1, false, true);
  __syncthreads();
  zero_acc(); matmul(wp + 262144, KB16{});         // r1_W2
  __syncthreads();
  epilogue_res(r1_b2);                             // -> global (coalesced f16)
  stage_input();                                   // restore my_input
  __syncthreads();
  // --- main chain ---
  zero_acc(); matmul(wp + 131072, KB8{});          // proj
  __syncthreads();
  epilogue(proj_b, false, true);
  __syncthreads();
  for (int k = 0; k < 6; ++k) {
    zero_acc();
    matmul(wp + 524288 + (size_t)k*262144, KB16{});
    __syncthreads();
    epilogue(layers_b + k*512, k == 2, k < 5);     // res added at k==2
    __syncthreads();
  }
  // --- final dot: out5 @ out_W + out_b ---
  {
    int rr = tid >> 2, qq = tid & 3;
    float s = 0.f;
    const _Float16* arow = &A[rr*MSTR + qq*128];
    const float* owq = out_W + qq*128;
    for (int c = 0; c < 128; c += 4) {
      h4 v = *(const h4*)(arow + c);
      s += (float)v[0]*owq[c] + (float)v[1]*owq[c+1]
         + (float)v[2]*owq[c+2] + (float)v[3]*owq[c+3];
    }
    s += __shfl_xor(s, 1);
    s += __shfl_xor(s, 2);
    if (qq == 0) out[R0 + rr] = s + out_b[0];
  }
}

extern "C" void kernel_launch(void* const* d_in, const int* in_sizes, int n_in,
                              void* d_out, int out_size, void* d_ws, size_t ws_size,
                              hipStream_t stream) {
  const float* input_stuff = (const float*)d_in[0];
  const float* sound_loc   = (const float*)d_in[1];
  const float* grid_coors  = (const float*)d_in[2];
  const float* grid_0      = (const float*)d_in[3];
  const float* xyz_offset  = (const float*)d_in[4];
  const float* bandwidths  = (const float*)d_in[5];
  const float* proj_W  = (const float*)d_in[6];
  const float* proj_b  = (const float*)d_in[7];
  const float* r1_W1   = (const float*)d_in[8];
  const float* r1_b1   = (const float*)d_in[9];
  const float* r1_W2   = (const float*)d_in[10];
  const float* r1_b2   = (const float*)d_in[11];
  const float* layers_W = (const float*)d_in[12];
  const float* layers_b = (const float*)d_in[13];
  const float* out_W   = (const float*)d_in[14];
  const float* out_b   = (const float*)d_in[15];

  char* ws = (char*)d_ws;
  float*     gf  = (float*)ws;                    // [16][128] fp32   (8 KB)
  float*     wn  = (float*)(ws + (64 << 10));     // [32][6912] fp32  (884 KB)
  _Float16*  wp  = (_Float16*)(ws + (1 << 20));   // packed weights   (4 MB)
  _Float16*  res = (_Float16*)(ws + (8 << 20));   // res spill f16    (64 MB)
  float* out = (float*)d_out;

  (void)hipMemsetAsync(gf, 0, 16*128*sizeof(float), stream);
  hipLaunchKernelGGL(k_gridA, dim3(32), dim3(256), 0, stream,
                     sound_loc, grid_coors, xyz_offset, bandwidths, wn);
  hipLaunchKernelGGL(k_gridB, dim3(16, 32), dim3(256), 0, stream,
                     wn, grid_0, gf);
  hipLaunchKernelGGL(k_pack, dim3(128), dim3(256), 0, stream,
                     r1_W1, proj_W, r1_W2, layers_W, wp);
  hipLaunchKernelGGL(k_mlp, dim3(512), dim3(512), 0, stream,
                     input_stuff, gf, wp, proj_b, r1_b1, r1_b2, layers_b,
                     out_W, out_b, res, out);
}